// Round 2
// baseline (1810.917 us; speedup 1.0000x reference)
//
#include <hip/hip_runtime.h>

typedef unsigned short u16;
typedef unsigned int u32;

#define N_ATOMS 100000
#define N_BONDS 200000
#define N_EDGES 100000
#define HIDDEN 300
#define HP 320
#define ATOM_FDIM 133
#define BOND_FDIM 147
#define CATP 448
#define N_MOLS 2000

typedef __bf16 bf16x8 __attribute__((ext_vector_type(8)));
typedef float f32x4 __attribute__((ext_vector_type(4)));

__device__ __forceinline__ u16 f2bf(float f) {
    union { float f; u32 u; } x; x.f = f;
    u32 u = x.u;
    u32 r = u + 0x7fffu + ((u >> 16) & 1u);
    return (u16)(r >> 16);
}
__device__ __forceinline__ float bf2f(u16 h) {
    union { u32 u; float f; } x; x.u = ((u32)h) << 16;
    return x.f;
}

union U8 { uint4 v; u16 h[8]; };

// ======================= fused-staging bf16 MFMA GEMM =======================
// One block: 64 rows x 320 cols (full N). 256 threads = 4 waves, wave wc owns
// cols [wc*80, wc*80+80). A-operand built on the fly per ASRC:
//  ASRC 0: plain bf16, stride lda
//  ASRC 1: f32 source (f_bonds), real width lda, zero-pad to K
//  ASRC 2: delta = amsg[b2a[r]] - relu(h[b2revb[r]])        (bf16, stride HP)
//  ASRC 3: cat   = [amsg[r] (300) | 0 x4 | f32 f_atoms[r] (133) | 0 pad]
//  ASRC 4: havg  = 0.5*(ah[b2a[2r]] + ah[b2a[b2revb[2r]]])
// Epilogue EP:
//  0: Cf[grow*ldc+gcol] = acc + bias[gcol]        (gcol < Nout, f32 out)
//  1: O1 = bf16(acc)                              (stride HP)
//  2: O1 = bf16(acc + bf2f(inp_in[...]))          (stride HP, pre-relu stored)
//  3: O1 = bf16(relu(acc + (gcol<Nout?bias:0)))   (stride HP)
template<int ASRC, int EP>
__global__ __launch_bounds__(256) void k_gemm(
    const float* __restrict__ fsrc, const u16* __restrict__ src16,
    const u16* __restrict__ src16b, const int* __restrict__ i1,
    const int* __restrict__ i2, int lda, int M,
    const u16* __restrict__ Bt, int ldb, int K,
    int Nout, float* __restrict__ Cf, int ldc,
    const float* __restrict__ bias, u16* __restrict__ O1,
    const u16* __restrict__ inp_in)
{
    __shared__ __align__(16) u16 As[64 * 40];
    __shared__ __align__(16) u16 Bs[320 * 40];

    const int tid = threadIdx.x;
    const int row0 = blockIdx.x * 64;
    const int lane = tid & 63;
    const int wc = tid >> 6;
    const int lrow = lane & 15, lkb = (lane >> 4) * 8;

    // ---- staging setup: thread -> (row rr, k-group kg) ----
    const int rr = tid >> 2, kg = tid & 3, kofs = kg * 8;
    int r = row0 + rr; if (r >= M) r = M - 1;

    const u16* pa = nullptr;
    const u16* pa2 = nullptr;
    size_t fbase = 0;
    if constexpr (ASRC == 0) pa = src16 + (size_t)r * lda + kofs;
    if constexpr (ASRC == 1) fbase = (size_t)r * lda;
    if constexpr (ASRC == 2) {
        pa  = src16  + (size_t)i1[r] * HP + kofs;
        pa2 = src16b + (size_t)i2[r] * HP + kofs;
    }
    if constexpr (ASRC == 3) { pa = src16 + (size_t)r * HP; fbase = (size_t)r * ATOM_FDIM; }
    if constexpr (ASRC == 4) {
        int e1 = 2 * r;
        int a1 = i1[e1];
        int a2 = i1[i2[e1]];
        pa  = src16 + (size_t)a1 * HP + kofs;
        pa2 = src16 + (size_t)a2 * HP + kofs;
    }

    auto loadA = [&](int k0) -> uint4 {
        U8 u;
        if constexpr (ASRC == 0) {
            u.v = *(const uint4*)(pa + k0);
        } else if constexpr (ASRC == 1) {
#pragma unroll
            for (int e = 0; e < 8; e++) {
                int col = k0 + kofs + e;
                u.h[e] = (col < lda) ? f2bf(fsrc[fbase + col]) : (u16)0;
            }
        } else if constexpr (ASRC == 2) {
            U8 x, y; x.v = *(const uint4*)(pa + k0); y.v = *(const uint4*)(pa2 + k0);
#pragma unroll
            for (int e = 0; e < 8; e++)
                u.h[e] = f2bf(bf2f(x.h[e]) - fmaxf(bf2f(y.h[e]), 0.f));
        } else if constexpr (ASRC == 3) {
#pragma unroll
            for (int e = 0; e < 8; e++) {
                int col = k0 + kofs + e;
                if (col < HIDDEN) u.h[e] = pa[col];
                else if (col >= 304 && col < 304 + ATOM_FDIM) u.h[e] = f2bf(fsrc[fbase + col - 304]);
                else u.h[e] = 0;
            }
        } else {
            U8 x, y; x.v = *(const uint4*)(pa + k0); y.v = *(const uint4*)(pa2 + k0);
#pragma unroll
            for (int e = 0; e < 8; e++)
                u.h[e] = f2bf(0.5f * (bf2f(x.h[e]) + bf2f(y.h[e])));
        }
        return u.v;
    };

    // B staging: 320 rows x 4 kgroups = 1280 chunks, 5 per thread
    const u16* pb[5];
#pragma unroll
    for (int j = 0; j < 5; j++)
        pb[j] = Bt + (size_t)(rr + 64 * j) * ldb + kofs;

    uint4 va = loadA(0);
    uint4 vb[5];
#pragma unroll
    for (int j = 0; j < 5; j++) vb[j] = *(const uint4*)pb[j];

    f32x4 acc[4][5] = {};

    for (int k0 = 0; k0 < K; k0 += 32) {
        *(uint4*)&As[rr * 40 + kofs] = va;
#pragma unroll
        for (int j = 0; j < 5; j++)
            *(uint4*)&Bs[(rr + 64 * j) * 40 + kofs] = vb[j];
        __syncthreads();
        if (k0 + 32 < K) {
            va = loadA(k0 + 32);
#pragma unroll
            for (int j = 0; j < 5; j++) vb[j] = *(const uint4*)(pb[j] + k0 + 32);
        }
        bf16x8 af[4], bfr[5];
#pragma unroll
        for (int m = 0; m < 4; m++)
            af[m] = *(const bf16x8*)&As[(m * 16 + lrow) * 40 + lkb];
#pragma unroll
        for (int n = 0; n < 5; n++)
            bfr[n] = *(const bf16x8*)&Bs[(wc * 80 + n * 16 + lrow) * 40 + lkb];
#pragma unroll
        for (int m = 0; m < 4; m++)
#pragma unroll
            for (int n = 0; n < 5; n++)
                acc[m][n] = __builtin_amdgcn_mfma_f32_16x16x32_bf16(af[m], bfr[n], acc[m][n], 0, 0, 0);
        __syncthreads();
    }

    const int orow = (lane >> 4) * 4;
    const int ocol = lane & 15;
#pragma unroll
    for (int m = 0; m < 4; m++) {
#pragma unroll
        for (int n = 0; n < 5; n++) {
#pragma unroll
            for (int q = 0; q < 4; q++) {
                int grow = row0 + m * 16 + orow + q;
                int gcol = wc * 80 + n * 16 + ocol;
                float v = acc[m][n][q];
                if (EP == 0) {
                    if (grow < M && gcol < Nout)
                        Cf[(size_t)grow * ldc + gcol] = v + bias[gcol];
                } else if (EP == 1) {
                    if (grow < M) O1[(size_t)grow * HP + gcol] = f2bf(v);
                } else if (EP == 2) {
                    if (grow < M) {
                        float x = v + bf2f(inp_in[(size_t)grow * HP + gcol]);
                        O1[(size_t)grow * HP + gcol] = f2bf(x);
                    }
                } else {
                    if (grow < M) {
                        float x = v + (gcol < Nout ? bias[gcol] : 0.f);
                        O1[(size_t)grow * HP + gcol] = f2bf(fmaxf(x, 0.f));
                    }
                }
            }
        }
    }
}

// ---------------- weight pack: Bt[n][k] = W[k][n], bf16, zero-padded ----------------
__global__ void k_pack_wt(const float* __restrict__ W, u16* __restrict__ Bt,
                          int K, int N, int Kp, int Np)
{
    int idx = blockIdx.x * 256 + threadIdx.x;
    if (idx >= Np * Kp) return;
    int n = idx / Kp, k = idx - n * Kp;
    Bt[idx] = (n < N && k < K) ? f2bf(W[(size_t)k * N + n]) : (u16)0;
}

// W_o pack with the [amsg | pad4 | f_atoms] column reorder
__global__ void k_pack_wo(const float* __restrict__ W, u16* __restrict__ Bt)
{
    int idx = blockIdx.x * 256 + threadIdx.x;
    if (idx >= 320 * CATP) return;
    int n = idx / CATP, k = idx - n * CATP;
    float v = 0.f;
    if (n < HIDDEN) {
        if (k < HIDDEN) v = W[(size_t)(ATOM_FDIM + k) * HIDDEN + n];
        else if (k >= 304 && k < 304 + ATOM_FDIM) v = W[(size_t)(k - 304) * HIDDEN + n];
    }
    Bt[idx] = f2bf(v);
}

// ---------------- a_msg[a] = sum_j relu(h[a2b[a][j]]) ----------------
__global__ __launch_bounds__(256) void k_aggregate(const u16* __restrict__ h,
    const int* __restrict__ a2b, u16* __restrict__ amsg)
{
    int idx = blockIdx.x * 256 + threadIdx.x;
    if (idx >= N_ATOMS * 40) return;
    int a = idx / 40, c = (idx - a * 40) * 8;
    float s[8] = {};
#pragma unroll
    for (int j = 0; j < 6; j++) {
        int b = a2b[a * 6 + j];
        U8 u; u.v = *(const uint4*)&h[(size_t)b * HP + c];
#pragma unroll
        for (int i = 0; i < 8; i++) s[i] += fmaxf(bf2f(u.h[i]), 0.f);
    }
    U8 o;
#pragma unroll
    for (int i = 0; i < 8; i++) o.h[i] = f2bf(s[i]);
    *(uint4*)&amsg[(size_t)a * HP + c] = o.v;
}

// ---------------- per-molecule segment sum (graph_idx sorted) ----------------
__device__ __forceinline__ int lower_bound_i(const int* a, int n, int v) {
    int lo = 0, hi = n;
    while (lo < hi) { int mid = (lo + hi) >> 1; if (a[mid] < v) lo = mid + 1; else hi = mid; }
    return lo;
}
__global__ __launch_bounds__(320) void k_segsum(const u16* __restrict__ ah,
    const int* __restrict__ gidx, float* __restrict__ gemb)
{
    int g = blockIdx.x;
    int c = threadIdx.x;
    int s = lower_bound_i(gidx, N_ATOMS, g);
    int e = lower_bound_i(gidx, N_ATOMS, g + 1);
    float sum = 0.f;
    for (int a = s; a < e; a++) sum += bf2f(ah[(size_t)a * HP + c]);
    gemb[(size_t)g * HP + c] = sum;
}

// ---------------- graph head (fp32) ----------------
__global__ __launch_bounds__(320) void k_g1(const float* __restrict__ gemb,
    const float* __restrict__ W, const float* __restrict__ b, float* __restrict__ gh)
{
    int g = blockIdx.x, j = threadIdx.x;
    float acc = 0.f;
    if (j < HIDDEN) {
        acc = b[j];
        for (int k = 0; k < HIDDEN; k++)
            acc = fmaf(gemb[(size_t)g * HP + k], W[(size_t)k * HIDDEN + j], acc);
        acc = fmaxf(acc, 0.f);
    }
    gh[(size_t)g * HP + j] = (j < HIDDEN) ? acc : 0.f;
}
__global__ __launch_bounds__(64) void k_g2(const float* __restrict__ gh,
    const float* __restrict__ W, const float* __restrict__ b, float* __restrict__ out)
{
    int g = blockIdx.x, l = threadIdx.x;
    float acc = 0.f;
    for (int j = l; j < HIDDEN; j += 64) acc += gh[(size_t)g * HP + j] * W[j];
#pragma unroll
    for (int off = 32; off; off >>= 1) acc += __shfl_down(acc, off, 64);
    if (l == 0) out[g] = acc + b[0];
}

extern "C" void kernel_launch(void* const* d_in, const int* in_sizes, int n_in,
                              void* d_out, int out_size, void* d_ws, size_t ws_size,
                              hipStream_t stream)
{
    const float* f_atoms = (const float*)d_in[0];
    const float* f_bonds = (const float*)d_in[1];
    const int* a2b    = (const int*)d_in[2];
    const int* b2a    = (const int*)d_in[3];
    const int* b2revb = (const int*)d_in[4];
    const int* gidx   = (const int*)d_in[5];
    const float* W_i    = (const float*)d_in[6];
    const float* W_h    = (const float*)d_in[7];
    const float* W_o    = (const float*)d_in[8];
    const float* b_o    = (const float*)d_in[9];
    const float* W_node = (const float*)d_in[10];
    const float* b_node = (const float*)d_in[11];
    const float* W_edge = (const float*)d_in[12];
    const float* b_edge = (const float*)d_in[13];
    const float* W_g1   = (const float*)d_in[14];
    const float* b_g1   = (const float*)d_in[15];
    const float* W_g2   = (const float*)d_in[16];
    const float* b_g2   = (const float*)d_in[17];

    char* ws = (char*)d_ws;
    u16* inp  = (u16*)(ws + 0);            // 128 MB (= h1, pre-relu)
    u16* hA   = (u16*)(ws + 128000000);    // 128 MB; reused as ah
    u16* hB   = (u16*)(ws + 256000000);    // 128 MB
    u16* amsg = (u16*)(ws + 384000000);    // 64 MB
    u16* wt_i = (u16*)(ws + 448000000);    // 320x160
    u16* wt_h = (u16*)(ws + 448200000);    // 320x320
    u16* wt_o = (u16*)(ws + 448500000);    // 320x448
    u16* wt_n = (u16*)(ws + 448800000);    // 320x320
    u16* wt_e = (u16*)(ws + 449050000);    // 320x320
    float* gemb = (float*)(ws + 449300000); // 2000x320 f32
    float* gh   = (float*)(ws + 452000000); // 2000x320 f32

    float* out_node  = (float*)d_out;
    float* out_edge  = out_node + (size_t)N_ATOMS * ATOM_FDIM;
    float* out_graph = out_node + 14700000;

    dim3 blk(256);

    // pack weights (bf16, transposed, padded to Np=320 rows)
    k_pack_wt<<<(320 * 160 + 255) / 256, blk, 0, stream>>>(W_i, wt_i, BOND_FDIM, HIDDEN, 160, 320);
    k_pack_wt<<<(320 * 320 + 255) / 256, blk, 0, stream>>>(W_h, wt_h, HIDDEN, HIDDEN, 320, 320);
    k_pack_wo<<<(320 * CATP + 255) / 256, blk, 0, stream>>>(W_o, wt_o);
    k_pack_wt<<<(320 * 320 + 255) / 256, blk, 0, stream>>>(W_node, wt_n, HIDDEN, ATOM_FDIM, 320, 320);
    k_pack_wt<<<(320 * 320 + 255) / 256, blk, 0, stream>>>(W_edge, wt_e, HIDDEN, 14, 320, 320);

    const int gB = (N_BONDS + 63) / 64;   // 3125
    const int gAt = (N_ATOMS + 63) / 64;  // 1563
    const int gAg = (N_ATOMS * 40 + 255) / 256;

    // inp = f_bonds @ W_i   (fused f32->bf16 pack in staging; pre-relu stored)
    k_gemm<1, 1><<<gB, blk, 0, stream>>>(
        f_bonds, nullptr, nullptr, nullptr, nullptr, BOND_FDIM, N_BONDS,
        wt_i, 160, 160, 0, nullptr, 0, nullptr, inp, nullptr);

    // depth loop: h_{d+1} = inp + (amsg[b2a] - relu(h_d[b2revb])) @ W_h
    const u16* hcur = inp;
    u16* houts[2] = { hA, hB };
    for (int d = 0; d < 2; ++d) {
        k_aggregate<<<gAg, blk, 0, stream>>>(hcur, a2b, amsg);
        k_gemm<2, 2><<<gB, blk, 0, stream>>>(
            nullptr, amsg, hcur, b2a, b2revb, 0, N_BONDS,
            wt_h, 320, 320, 0, nullptr, 0, nullptr, houts[d], inp);
        hcur = houts[d];
    }

    // final aggregate + fused-concat W_o -> atom_hiddens (relu'd, bf16)
    k_aggregate<<<gAg, blk, 0, stream>>>(hcur, a2b, amsg);
    u16* ah = hA; // hA free after d=1 GEMM consumed it
    k_gemm<3, 3><<<gAt, blk, 0, stream>>>(
        f_atoms, amsg, nullptr, nullptr, nullptr, 0, N_ATOMS,
        wt_o, CATP, CATP, HIDDEN, nullptr, 0, b_o, ah, nullptr);

    // node head
    k_gemm<0, 0><<<gAt, blk, 0, stream>>>(
        nullptr, ah, nullptr, nullptr, nullptr, HP, N_ATOMS,
        wt_n, 320, 320, ATOM_FDIM, out_node, ATOM_FDIM, b_node, nullptr, nullptr);

    // edge head (fused h_avg gather in staging)
    k_gemm<4, 0><<<gAt, blk, 0, stream>>>(
        nullptr, ah, nullptr, b2a, b2revb, 0, N_EDGES,
        wt_e, 320, 320, 14, out_edge, 14, b_edge, nullptr, nullptr);

    // graph head
    k_segsum<<<N_MOLS, 320, 0, stream>>>(ah, gidx, gemb);
    k_g1<<<N_MOLS, 320, 0, stream>>>(gemb, W_g1, b_g1, gh);
    k_g2<<<N_MOLS, 64, 0, stream>>>(gh, W_g2, b_g2, out_graph);
}

// Round 3
// 1802.414 us; speedup vs baseline: 1.0047x; 1.0047x over previous
//
#include <hip/hip_runtime.h>

typedef unsigned short u16;
typedef unsigned int u32;

#define N_ATOMS 100000
#define N_BONDS 200000
#define N_EDGES 100000
#define HIDDEN 300
#define HP 320
#define ATOM_FDIM 133
#define BOND_FDIM 147
#define CATP 448
#define N_MOLS 2000

typedef __bf16 bf16x8 __attribute__((ext_vector_type(8)));
typedef float f32x4 __attribute__((ext_vector_type(4)));

__device__ __forceinline__ u16 f2bf(float f) {
    union { float f; u32 u; } x; x.f = f;
    u32 u = x.u;
    u32 r = u + 0x7fffu + ((u >> 16) & 1u);
    return (u16)(r >> 16);
}
__device__ __forceinline__ float bf2f(u16 h) {
    union { u32 u; float f; } x; x.u = ((u32)h) << 16;
    return x.f;
}

union U8 { uint4 v; u16 h[8]; };

// A-operand fused load: one 16B chunk (8 bf16) at k-offset k0+kofs for one row.
//  ASRC 0: plain bf16 row (pa = row base + kofs)
//  ASRC 1: f32 source row (fsrc+fbase), width lda, zero-pad
//  ASRC 2: delta = amsg[b2a[r]] - relu(h[b2revb[r]])  (pa, pa2 pre-gathered)
//  ASRC 3: cat   = [amsg[r] (300) | 0 x4 | f32 f_atoms[r] (133) | 0 pad]
//  ASRC 4: havg  = 0.5*(ah[a1] + ah[a2])
template<int ASRC>
__device__ __forceinline__ uint4 loadA(const float* __restrict__ fsrc, size_t fbase,
    const u16* __restrict__ pa, const u16* __restrict__ pa2,
    int lda, int kofs, int k0)
{
    U8 u;
    if constexpr (ASRC == 0) {
        u.v = *(const uint4*)(pa + k0);
    } else if constexpr (ASRC == 1) {
#pragma unroll
        for (int e = 0; e < 8; e++) {
            int col = k0 + kofs + e;
            u.h[e] = (col < lda) ? f2bf(fsrc[fbase + col]) : (u16)0;
        }
    } else if constexpr (ASRC == 2) {
        U8 x, y; x.v = *(const uint4*)(pa + k0); y.v = *(const uint4*)(pa2 + k0);
#pragma unroll
        for (int e = 0; e < 8; e++)
            u.h[e] = f2bf(bf2f(x.h[e]) - fmaxf(bf2f(y.h[e]), 0.f));
    } else if constexpr (ASRC == 3) {
#pragma unroll
        for (int e = 0; e < 8; e++) {
            int col = k0 + kofs + e;
            if (col < HIDDEN) u.h[e] = pa[col];
            else if (col >= 304 && col < 304 + ATOM_FDIM) u.h[e] = f2bf(fsrc[fbase + col - 304]);
            else u.h[e] = 0;
        }
    } else {
        U8 x, y; x.v = *(const uint4*)(pa + k0); y.v = *(const uint4*)(pa2 + k0);
#pragma unroll
        for (int e = 0; e < 8; e++)
            u.h[e] = f2bf(0.5f * (bf2f(x.h[e]) + bf2f(y.h[e])));
    }
    return u.v;
}

// ======================= fused-staging bf16 MFMA GEMM =======================
// Block: 128 rows x 64 cols, 256 threads = 4 waves (2x2). blockIdx.x = N-block
// (fastest-varying -> A-panel reuse in L2/L3), blockIdx.y = M-block.
// Epilogue EP:
//  0: Cf[grow*ldc+gcol] = acc + bias[gcol]        (gcol < Nout, f32 out)
//  1: O1 = bf16(acc)                              (stride HP)
//  2: O1 = bf16(acc + bf2f(inp_in[...]))          (stride HP, pre-relu stored)
//  3: O1 = bf16(relu(acc + (gcol<Nout?bias:0)))   (stride HP)
template<int ASRC, int EP>
__global__ __launch_bounds__(256) void k_gemm(
    const float* __restrict__ fsrc, const u16* __restrict__ src16,
    const u16* __restrict__ src16b, const int* __restrict__ i1,
    const int* __restrict__ i2, int lda, int M,
    const u16* __restrict__ Bt, int ldb, int K,
    int Nout, float* __restrict__ Cf, int ldc,
    const float* __restrict__ bias, u16* __restrict__ O1,
    const u16* __restrict__ inp_in)
{
    __shared__ __align__(16) u16 As[128 * 40];
    __shared__ __align__(16) u16 Bs[64 * 40];

    const int tid = threadIdx.x;
    const int n0 = blockIdx.x * 64;
    const int row0 = blockIdx.y * 128;
    const int lane = tid & 63;
    const int w = tid >> 6, wr = w >> 1, wc = w & 1;
    const int lrow = lane & 15, lkb = (lane >> 4) * 8;

    // staging: A = 128 rows x 4 kgroups = 512 chunks (2/thread), B = 256 chunks
    const int rA0 = tid >> 2, kg = tid & 3, kofs = kg * 8;
    const int rA1 = rA0 + 64;

    int r0 = row0 + rA0; if (r0 >= M) r0 = M - 1;
    int r1 = row0 + rA1; if (r1 >= M) r1 = M - 1;

    const u16* pa0 = nullptr; const u16* pa0b = nullptr; size_t fb0 = 0;
    const u16* pa1 = nullptr; const u16* pa1b = nullptr; size_t fb1 = 0;
    if constexpr (ASRC == 0) {
        pa0 = src16 + (size_t)r0 * lda + kofs;
        pa1 = src16 + (size_t)r1 * lda + kofs;
    }
    if constexpr (ASRC == 1) { fb0 = (size_t)r0 * lda; fb1 = (size_t)r1 * lda; }
    if constexpr (ASRC == 2) {
        pa0  = src16  + (size_t)i1[r0] * HP + kofs;
        pa0b = src16b + (size_t)i2[r0] * HP + kofs;
        pa1  = src16  + (size_t)i1[r1] * HP + kofs;
        pa1b = src16b + (size_t)i2[r1] * HP + kofs;
    }
    if constexpr (ASRC == 3) {
        pa0 = src16 + (size_t)r0 * HP; fb0 = (size_t)r0 * ATOM_FDIM;
        pa1 = src16 + (size_t)r1 * HP; fb1 = (size_t)r1 * ATOM_FDIM;
    }
    if constexpr (ASRC == 4) {
        int e0 = 2 * r0, e1 = 2 * r1;
        pa0  = src16 + (size_t)i1[e0] * HP + kofs;
        pa0b = src16 + (size_t)i1[i2[e0]] * HP + kofs;
        pa1  = src16 + (size_t)i1[e1] * HP + kofs;
        pa1b = src16 + (size_t)i1[i2[e1]] * HP + kofs;
    }

    const u16* pb = Bt + (size_t)(n0 + rA0) * ldb + kofs;

    uint4 va0 = loadA<ASRC>(fsrc, fb0, pa0, pa0b, lda, kofs, 0);
    uint4 va1 = loadA<ASRC>(fsrc, fb1, pa1, pa1b, lda, kofs, 0);
    uint4 vb  = *(const uint4*)pb;

    f32x4 acc[4][2] = {};

    for (int k0 = 0; k0 < K; k0 += 32) {
        *(uint4*)&As[rA0 * 40 + kofs] = va0;
        *(uint4*)&As[rA1 * 40 + kofs] = va1;
        *(uint4*)&Bs[rA0 * 40 + kofs] = vb;
        __syncthreads();
        if (k0 + 32 < K) {
            va0 = loadA<ASRC>(fsrc, fb0, pa0, pa0b, lda, kofs, k0 + 32);
            va1 = loadA<ASRC>(fsrc, fb1, pa1, pa1b, lda, kofs, k0 + 32);
            vb  = *(const uint4*)(pb + k0 + 32);
        }
        bf16x8 af[4], bfr[2];
#pragma unroll
        for (int m = 0; m < 4; m++)
            af[m] = *(const bf16x8*)&As[(wr * 64 + m * 16 + lrow) * 40 + lkb];
#pragma unroll
        for (int n = 0; n < 2; n++)
            bfr[n] = *(const bf16x8*)&Bs[(wc * 32 + n * 16 + lrow) * 40 + lkb];
#pragma unroll
        for (int m = 0; m < 4; m++)
#pragma unroll
            for (int n = 0; n < 2; n++)
                acc[m][n] = __builtin_amdgcn_mfma_f32_16x16x32_bf16(af[m], bfr[n], acc[m][n], 0, 0, 0);
        __syncthreads();
    }

    const int orow = (lane >> 4) * 4;
    const int ocol = lane & 15;
#pragma unroll
    for (int m = 0; m < 4; m++) {
#pragma unroll
        for (int n = 0; n < 2; n++) {
#pragma unroll
            for (int q = 0; q < 4; q++) {
                int grow = row0 + wr * 64 + m * 16 + orow + q;
                int gcol = n0 + wc * 32 + n * 16 + ocol;
                float v = acc[m][n][q];
                if (EP == 0) {
                    if (grow < M && gcol < Nout)
                        Cf[(size_t)grow * ldc + gcol] = v + bias[gcol];
                } else if (EP == 1) {
                    if (grow < M) O1[(size_t)grow * HP + gcol] = f2bf(v);
                } else if (EP == 2) {
                    if (grow < M) {
                        float x = v + bf2f(inp_in[(size_t)grow * HP + gcol]);
                        O1[(size_t)grow * HP + gcol] = f2bf(x);
                    }
                } else {
                    if (grow < M) {
                        float x = v + (gcol < Nout ? bias[gcol] : 0.f);
                        O1[(size_t)grow * HP + gcol] = f2bf(fmaxf(x, 0.f));
                    }
                }
            }
        }
    }
}

// ---------------- weight pack: Bt[n][k] = W[k][n], bf16, zero-padded ----------------
__global__ void k_pack_wt(const float* __restrict__ W, u16* __restrict__ Bt,
                          int K, int N, int Kp, int Np)
{
    int idx = blockIdx.x * 256 + threadIdx.x;
    if (idx >= Np * Kp) return;
    int n = idx / Kp, k = idx - n * Kp;
    Bt[idx] = (n < N && k < K) ? f2bf(W[(size_t)k * N + n]) : (u16)0;
}

// W_o pack with the [amsg(300) | pad4 | f_atoms(133) | pad] column reorder
__global__ void k_pack_wo(const float* __restrict__ W, u16* __restrict__ Bt)
{
    int idx = blockIdx.x * 256 + threadIdx.x;
    if (idx >= 320 * CATP) return;
    int n = idx / CATP, k = idx - n * CATP;
    float v = 0.f;
    if (n < HIDDEN) {
        if (k < HIDDEN) v = W[(size_t)(ATOM_FDIM + k) * HIDDEN + n];
        else if (k >= 304 && k < 304 + ATOM_FDIM) v = W[(size_t)(k - 304) * HIDDEN + n];
    }
    Bt[idx] = f2bf(v);
}

// ---------------- a_msg[a] = sum_j relu(h[a2b[a][j]]) ----------------
__global__ __launch_bounds__(256) void k_aggregate(const u16* __restrict__ h,
    const int* __restrict__ a2b, u16* __restrict__ amsg)
{
    int idx = blockIdx.x * 256 + threadIdx.x;
    if (idx >= N_ATOMS * 40) return;
    int a = idx / 40, c = (idx - a * 40) * 8;
    float s[8] = {};
#pragma unroll
    for (int j = 0; j < 6; j++) {
        int b = a2b[a * 6 + j];
        U8 u; u.v = *(const uint4*)&h[(size_t)b * HP + c];
#pragma unroll
        for (int i = 0; i < 8; i++) s[i] += fmaxf(bf2f(u.h[i]), 0.f);
    }
    U8 o;
#pragma unroll
    for (int i = 0; i < 8; i++) o.h[i] = f2bf(s[i]);
    *(uint4*)&amsg[(size_t)a * HP + c] = o.v;
}

// ---------------- per-molecule segment sum (graph_idx sorted) ----------------
__device__ __forceinline__ int lower_bound_i(const int* a, int n, int v) {
    int lo = 0, hi = n;
    while (lo < hi) { int mid = (lo + hi) >> 1; if (a[mid] < v) lo = mid + 1; else hi = mid; }
    return lo;
}
__global__ __launch_bounds__(320) void k_segsum(const u16* __restrict__ ah,
    const int* __restrict__ gidx, float* __restrict__ gemb)
{
    int g = blockIdx.x;
    int c = threadIdx.x;
    int s = lower_bound_i(gidx, N_ATOMS, g);
    int e = lower_bound_i(gidx, N_ATOMS, g + 1);
    float sum = 0.f;
    for (int a = s; a < e; a++) sum += bf2f(ah[(size_t)a * HP + c]);
    gemb[(size_t)g * HP + c] = sum;
}

// ---------------- graph head (fp32) ----------------
__global__ __launch_bounds__(320) void k_g1(const float* __restrict__ gemb,
    const float* __restrict__ W, const float* __restrict__ b, float* __restrict__ gh)
{
    int g = blockIdx.x, j = threadIdx.x;
    float acc = 0.f;
    if (j < HIDDEN) {
        acc = b[j];
        for (int k = 0; k < HIDDEN; k++)
            acc = fmaf(gemb[(size_t)g * HP + k], W[(size_t)k * HIDDEN + j], acc);
        acc = fmaxf(acc, 0.f);
    }
    gh[(size_t)g * HP + j] = (j < HIDDEN) ? acc : 0.f;
}
__global__ __launch_bounds__(64) void k_g2(const float* __restrict__ gh,
    const float* __restrict__ W, const float* __restrict__ b, float* __restrict__ out)
{
    int g = blockIdx.x, l = threadIdx.x;
    float acc = 0.f;
    for (int j = l; j < HIDDEN; j += 64) acc += gh[(size_t)g * HP + j] * W[j];
#pragma unroll
    for (int off = 32; off; off >>= 1) acc += __shfl_down(acc, off, 64);
    if (l == 0) out[g] = acc + b[0];
}

extern "C" void kernel_launch(void* const* d_in, const int* in_sizes, int n_in,
                              void* d_out, int out_size, void* d_ws, size_t ws_size,
                              hipStream_t stream)
{
    const float* f_atoms = (const float*)d_in[0];
    const float* f_bonds = (const float*)d_in[1];
    const int* a2b    = (const int*)d_in[2];
    const int* b2a    = (const int*)d_in[3];
    const int* b2revb = (const int*)d_in[4];
    const int* gidx   = (const int*)d_in[5];
    const float* W_i    = (const float*)d_in[6];
    const float* W_h    = (const float*)d_in[7];
    const float* W_o    = (const float*)d_in[8];
    const float* b_o    = (const float*)d_in[9];
    const float* W_node = (const float*)d_in[10];
    const float* b_node = (const float*)d_in[11];
    const float* W_edge = (const float*)d_in[12];
    const float* b_edge = (const float*)d_in[13];
    const float* W_g1   = (const float*)d_in[14];
    const float* b_g1   = (const float*)d_in[15];
    const float* W_g2   = (const float*)d_in[16];
    const float* b_g2   = (const float*)d_in[17];

    char* ws = (char*)d_ws;
    u16* inp  = (u16*)(ws + 0);            // 128 MB (h1 pre-relu input term)
    u16* hA   = (u16*)(ws + 128000000);    // 128 MB; reused as ah
    u16* hB   = (u16*)(ws + 256000000);    // 128 MB
    u16* amsg = (u16*)(ws + 384000000);    // 64 MB
    u16* wt_i = (u16*)(ws + 448000000);    // 320x160
    u16* wt_h = (u16*)(ws + 448200000);    // 320x320
    u16* wt_o = (u16*)(ws + 448500000);    // 320x448
    u16* wt_n = (u16*)(ws + 448800000);    // 192x320
    u16* wt_e = (u16*)(ws + 449000000);    // 64x320
    float* gemb = (float*)(ws + 449300000); // 2000x320 f32
    float* gh   = (float*)(ws + 452000000); // 2000x320 f32

    float* out_node  = (float*)d_out;
    float* out_edge  = out_node + (size_t)N_ATOMS * ATOM_FDIM;
    float* out_graph = out_node + 14700000;

    dim3 blk(256);

    // pack weights (bf16, transposed, zero-padded)
    k_pack_wt<<<(320 * 160 + 255) / 256, blk, 0, stream>>>(W_i, wt_i, BOND_FDIM, HIDDEN, 160, 320);
    k_pack_wt<<<(320 * 320 + 255) / 256, blk, 0, stream>>>(W_h, wt_h, HIDDEN, HIDDEN, 320, 320);
    k_pack_wo<<<(320 * CATP + 255) / 256, blk, 0, stream>>>(W_o, wt_o);
    k_pack_wt<<<(192 * 320 + 255) / 256, blk, 0, stream>>>(W_node, wt_n, HIDDEN, ATOM_FDIM, 320, 192);
    k_pack_wt<<<(64 * 320 + 255) / 256, blk, 0, stream>>>(W_edge, wt_e, HIDDEN, 14, 320, 64);

    const int mbB = (N_BONDS + 127) / 128;  // 1563
    const int mbA = (N_ATOMS + 127) / 128;  // 782
    const int gAg = (N_ATOMS * 40 + 255) / 256;

    // inp = f_bonds @ W_i  (fused f32->bf16 pack in staging; pre-relu stored)
    k_gemm<1, 1><<<dim3(5, mbB), blk, 0, stream>>>(
        f_bonds, nullptr, nullptr, nullptr, nullptr, BOND_FDIM, N_BONDS,
        wt_i, 160, 160, 0, nullptr, 0, nullptr, inp, nullptr);

    // depth loop: h_{d+1} = inp + (amsg[b2a] - relu(h_d[b2revb])) @ W_h
    const u16* hcur = inp;
    u16* houts[2] = { hA, hB };
    for (int d = 0; d < 2; ++d) {
        k_aggregate<<<gAg, blk, 0, stream>>>(hcur, a2b, amsg);
        k_gemm<2, 2><<<dim3(5, mbB), blk, 0, stream>>>(
            nullptr, amsg, hcur, b2a, b2revb, 0, N_BONDS,
            wt_h, 320, 320, 0, nullptr, 0, nullptr, houts[d], inp);
        hcur = houts[d];
    }

    // final aggregate + fused-concat W_o -> atom_hiddens (relu'd, bf16)
    k_aggregate<<<gAg, blk, 0, stream>>>(hcur, a2b, amsg);
    u16* ah = hA; // free after d=1 GEMM consumed it
    k_gemm<3, 3><<<dim3(5, mbA), blk, 0, stream>>>(
        f_atoms, amsg, nullptr, nullptr, nullptr, 0, N_ATOMS,
        wt_o, CATP, CATP, HIDDEN, nullptr, 0, b_o, ah, nullptr);

    // node head
    k_gemm<0, 0><<<dim3(3, mbA), blk, 0, stream>>>(
        nullptr, ah, nullptr, nullptr, nullptr, HP, N_ATOMS,
        wt_n, 320, 320, ATOM_FDIM, out_node, ATOM_FDIM, b_node, nullptr, nullptr);

    // edge head (fused h_avg gather in staging)
    k_gemm<4, 0><<<dim3(1, mbA), blk, 0, stream>>>(
        nullptr, ah, nullptr, b2a, b2revb, 0, N_EDGES,
        wt_e, 320, 320, 14, out_edge, 14, b_edge, nullptr, nullptr);

    // graph head
    k_segsum<<<N_MOLS, 320, 0, stream>>>(ah, gidx, gemb);
    k_g1<<<N_MOLS, 320, 0, stream>>>(gemb, W_g1, b_g1, gh);
    k_g2<<<N_MOLS, 64, 0, stream>>>(gh, W_g2, b_g2, out_graph);
}

// Round 4
// 1552.986 us; speedup vs baseline: 1.1661x; 1.1606x over previous
//
#include <hip/hip_runtime.h>

typedef unsigned short u16;
typedef unsigned int u32;

#define N_ATOMS 100000
#define N_BONDS 200000
#define N_EDGES 100000
#define HIDDEN 300
#define HP 320
#define ATOM_FDIM 133
#define BOND_FDIM 147
#define CATP 448
#define N_MOLS 2000

typedef __bf16 bf16x8 __attribute__((ext_vector_type(8)));
typedef float f32x4 __attribute__((ext_vector_type(4)));

__device__ __forceinline__ u16 f2bf(float f) {
    union { float f; u32 u; } x; x.f = f;
    u32 u = x.u;
    u32 r = u + 0x7fffu + ((u >> 16) & 1u);
    return (u16)(r >> 16);
}
__device__ __forceinline__ float bf2f(u16 h) {
    union { u32 u; float f; } x; x.u = ((u32)h) << 16;
    return x.f;
}

union U8 { uint4 v; u16 h[8]; };

// =================== barrier-free direct-from-global MFMA GEMM ===================
// 256 threads = 4 waves. WAVEM=0: waves tile N (wave w -> cols w*NFW*16), block
// = 32 rows x 4*NFW*16 cols. WAVEM=1: waves tile M, block = 128 rows x NFW*16.
// No LDS, no __syncthreads: every lane loads its MFMA fragments directly from
// global (B is L2-resident; gathered A rows fetched once per block). A-operand
// fused per ASRC:
//  0: plain bf16 rows, stride lda
//  1: f32 rows (f_bonds), width lda, zero-pad to 32*KSTEPS
//  2: delta = amsg[i1[r]] - relu(h[i2[r]])
//  3: cat   = [amsg[r] (300) | 0 x4 | f32 f_atoms[r] (133) | 0 pad]
//  4: havg  = 0.5*(ah[i1[2r]] + ah[i1[i2[2r]]])
// Epilogue EP:
//  0: Cf[grow*ldc+gcol] = acc + bias[gcol]   (gcol<Nout, f32)
//  1: O1 = bf16(acc)
//  2: O1 = bf16(acc + bf2f(inp_in[...]))
//  3: O1 = bf16(relu(acc + (gcol<Nout?bias[gcol]:0)))
template<int ASRC, int EP, int KSTEPS, int NFW, int WAVEM>
__global__ __launch_bounds__(256) void k_gemm(
    const float* __restrict__ fsrc, const u16* __restrict__ src16,
    const u16* __restrict__ src16b, const int* __restrict__ i1,
    const int* __restrict__ i2, int lda, int M,
    const u16* __restrict__ Bt, int ldb,
    int Nout, float* __restrict__ Cf, int ldc,
    const float* __restrict__ bias, u16* __restrict__ O1,
    const u16* __restrict__ inp_in)
{
    const int tid = threadIdx.x;
    const int lane = tid & 63;
    const int w = tid >> 6;
    const int lrow = lane & 15;
    const int lkb = (lane >> 4) * 8;

    int row0, ncol0;
    if constexpr (WAVEM) { row0 = blockIdx.x * 128 + w * 32; ncol0 = 0; }
    else                 { row0 = blockIdx.x * 32;           ncol0 = w * (NFW * 16); }

    // per-m-frag A pointers (gathers resolved once)
    const u16* pa[2] = {nullptr, nullptr};
    const u16* pa2[2] = {nullptr, nullptr};
    size_t fb[2] = {0, 0};
#pragma unroll
    for (int m = 0; m < 2; m++) {
        int r = row0 + m * 16 + lrow; if (r >= M) r = M - 1;
        if constexpr (ASRC == 0) pa[m] = src16 + (size_t)r * lda + lkb;
        if constexpr (ASRC == 1) fb[m] = (size_t)r * lda;
        if constexpr (ASRC == 2) {
            pa[m]  = src16  + (size_t)i1[r] * HP + lkb;
            pa2[m] = src16b + (size_t)i2[r] * HP + lkb;
        }
        if constexpr (ASRC == 3) { pa[m] = src16 + (size_t)r * HP; fb[m] = (size_t)r * ATOM_FDIM; }
        if constexpr (ASRC == 4) {
            int e = 2 * r;
            pa[m]  = src16 + (size_t)i1[e] * HP + lkb;
            pa2[m] = src16 + (size_t)i1[i2[e]] * HP + lkb;
        }
    }

    const u16* pb[NFW];
#pragma unroll
    for (int n = 0; n < NFW; n++)
        pb[n] = Bt + (size_t)(ncol0 + n * 16 + lrow) * ldb + lkb;

    auto loadAfrag = [&](int m, int k0) -> bf16x8 {
        U8 u;
        if constexpr (ASRC == 0) {
            u.v = *(const uint4*)(pa[m] + k0);
        } else if constexpr (ASRC == 1) {
#pragma unroll
            for (int e = 0; e < 8; e++) {
                int col = k0 + lkb + e;
                u.h[e] = (col < lda) ? f2bf(fsrc[fb[m] + col]) : (u16)0;
            }
        } else if constexpr (ASRC == 2) {
            U8 x, y; x.v = *(const uint4*)(pa[m] + k0); y.v = *(const uint4*)(pa2[m] + k0);
#pragma unroll
            for (int e = 0; e < 8; e++)
                u.h[e] = f2bf(bf2f(x.h[e]) - fmaxf(bf2f(y.h[e]), 0.f));
        } else if constexpr (ASRC == 3) {
#pragma unroll
            for (int e = 0; e < 8; e++) {
                int col = k0 + lkb + e;
                u16 v = 0;
                if (col < HIDDEN) v = pa[m][col];
                else if (col >= 304 && col < 304 + ATOM_FDIM) v = f2bf(fsrc[fb[m] + col - 304]);
                u.h[e] = v;
            }
        } else {
            U8 x, y; x.v = *(const uint4*)(pa[m] + k0); y.v = *(const uint4*)(pa2[m] + k0);
#pragma unroll
            for (int e = 0; e < 8; e++)
                u.h[e] = f2bf(0.5f * (bf2f(x.h[e]) + bf2f(y.h[e])));
        }
        return *(bf16x8*)&u;
    };

    f32x4 acc[2][NFW] = {};

#pragma unroll
    for (int ks = 0; ks < KSTEPS; ks++) {
        const int k0 = ks * 32;
        bf16x8 a0 = loadAfrag(0, k0);
        bf16x8 a1 = loadAfrag(1, k0);
        bf16x8 bfr[NFW];
#pragma unroll
        for (int n = 0; n < NFW; n++) bfr[n] = *(const bf16x8*)(pb[n] + k0);
#pragma unroll
        for (int n = 0; n < NFW; n++) {
            acc[0][n] = __builtin_amdgcn_mfma_f32_16x16x32_bf16(a0, bfr[n], acc[0][n], 0, 0, 0);
            acc[1][n] = __builtin_amdgcn_mfma_f32_16x16x32_bf16(a1, bfr[n], acc[1][n], 0, 0, 0);
        }
    }

    const int orow = (lane >> 4) * 4;
    const int ocol = lane & 15;
#pragma unroll
    for (int m = 0; m < 2; m++) {
#pragma unroll
        for (int n = 0; n < NFW; n++) {
#pragma unroll
            for (int q = 0; q < 4; q++) {
                int grow = row0 + m * 16 + orow + q;
                int gcol = ncol0 + n * 16 + ocol;
                float v = acc[m][n][q];
                if constexpr (EP == 0) {
                    if (grow < M && gcol < Nout)
                        Cf[(size_t)grow * ldc + gcol] = v + bias[gcol];
                } else if constexpr (EP == 1) {
                    if (grow < M) O1[(size_t)grow * HP + gcol] = f2bf(v);
                } else if constexpr (EP == 2) {
                    if (grow < M) {
                        float x = v + bf2f(inp_in[(size_t)grow * HP + gcol]);
                        O1[(size_t)grow * HP + gcol] = f2bf(x);
                    }
                } else {
                    if (grow < M) {
                        float x = v + (gcol < Nout ? bias[gcol] : 0.f);
                        O1[(size_t)grow * HP + gcol] = f2bf(fmaxf(x, 0.f));
                    }
                }
            }
        }
    }
}

// ---------------- weight pack: Bt[n][k] = W[k][n], bf16, zero-padded ----------------
__global__ void k_pack_wt(const float* __restrict__ W, u16* __restrict__ Bt,
                          int K, int N, int Kp, int Np)
{
    int idx = blockIdx.x * 256 + threadIdx.x;
    if (idx >= Np * Kp) return;
    int n = idx / Kp, k = idx - n * Kp;
    Bt[idx] = (n < N && k < K) ? f2bf(W[(size_t)k * N + n]) : (u16)0;
}

// W_o pack with the [amsg(300) | pad4 | f_atoms(133) | pad] column reorder
__global__ void k_pack_wo(const float* __restrict__ W, u16* __restrict__ Bt)
{
    int idx = blockIdx.x * 256 + threadIdx.x;
    if (idx >= 320 * CATP) return;
    int n = idx / CATP, k = idx - n * CATP;
    float v = 0.f;
    if (n < HIDDEN) {
        if (k < HIDDEN) v = W[(size_t)(ATOM_FDIM + k) * HIDDEN + n];
        else if (k >= 304 && k < 304 + ATOM_FDIM) v = W[(size_t)(k - 304) * HIDDEN + n];
    }
    Bt[idx] = f2bf(v);
}

// ---------------- a_msg[a] = sum_j relu(h[a2b[a][j]]) ----------------
__global__ __launch_bounds__(256) void k_aggregate(const u16* __restrict__ h,
    const int* __restrict__ a2b, u16* __restrict__ amsg)
{
    int idx = blockIdx.x * 256 + threadIdx.x;
    if (idx >= N_ATOMS * 40) return;
    int a = idx / 40, c = (idx - a * 40) * 8;
    float s[8] = {};
#pragma unroll
    for (int j = 0; j < 6; j++) {
        int b = a2b[a * 6 + j];
        U8 u; u.v = *(const uint4*)&h[(size_t)b * HP + c];
#pragma unroll
        for (int i = 0; i < 8; i++) s[i] += fmaxf(bf2f(u.h[i]), 0.f);
    }
    U8 o;
#pragma unroll
    for (int i = 0; i < 8; i++) o.h[i] = f2bf(s[i]);
    *(uint4*)&amsg[(size_t)a * HP + c] = o.v;
}

// ---------------- per-molecule segment sum (graph_idx sorted) ----------------
__device__ __forceinline__ int lower_bound_i(const int* a, int n, int v) {
    int lo = 0, hi = n;
    while (lo < hi) { int mid = (lo + hi) >> 1; if (a[mid] < v) lo = mid + 1; else hi = mid; }
    return lo;
}
__global__ __launch_bounds__(320) void k_segsum(const u16* __restrict__ ah,
    const int* __restrict__ gidx, float* __restrict__ gemb)
{
    int g = blockIdx.x;
    int c = threadIdx.x;
    int s = lower_bound_i(gidx, N_ATOMS, g);
    int e = lower_bound_i(gidx, N_ATOMS, g + 1);
    float sum = 0.f;
    for (int a = s; a < e; a++) sum += bf2f(ah[(size_t)a * HP + c]);
    gemb[(size_t)g * HP + c] = sum;
}

// ---------------- graph head (fp32) ----------------
__global__ __launch_bounds__(320) void k_g1(const float* __restrict__ gemb,
    const float* __restrict__ W, const float* __restrict__ b, float* __restrict__ gh)
{
    int g = blockIdx.x, j = threadIdx.x;
    float acc = 0.f;
    if (j < HIDDEN) {
        acc = b[j];
        for (int k = 0; k < HIDDEN; k++)
            acc = fmaf(gemb[(size_t)g * HP + k], W[(size_t)k * HIDDEN + j], acc);
        acc = fmaxf(acc, 0.f);
    }
    gh[(size_t)g * HP + j] = (j < HIDDEN) ? acc : 0.f;
}
__global__ __launch_bounds__(64) void k_g2(const float* __restrict__ gh,
    const float* __restrict__ W, const float* __restrict__ b, float* __restrict__ out)
{
    int g = blockIdx.x, l = threadIdx.x;
    float acc = 0.f;
    for (int j = l; j < HIDDEN; j += 64) acc += gh[(size_t)g * HP + j] * W[j];
#pragma unroll
    for (int off = 32; off; off >>= 1) acc += __shfl_down(acc, off, 64);
    if (l == 0) out[g] = acc + b[0];
}

extern "C" void kernel_launch(void* const* d_in, const int* in_sizes, int n_in,
                              void* d_out, int out_size, void* d_ws, size_t ws_size,
                              hipStream_t stream)
{
    const float* f_atoms = (const float*)d_in[0];
    const float* f_bonds = (const float*)d_in[1];
    const int* a2b    = (const int*)d_in[2];
    const int* b2a    = (const int*)d_in[3];
    const int* b2revb = (const int*)d_in[4];
    const int* gidx   = (const int*)d_in[5];
    const float* W_i    = (const float*)d_in[6];
    const float* W_h    = (const float*)d_in[7];
    const float* W_o    = (const float*)d_in[8];
    const float* b_o    = (const float*)d_in[9];
    const float* W_node = (const float*)d_in[10];
    const float* b_node = (const float*)d_in[11];
    const float* W_edge = (const float*)d_in[12];
    const float* b_edge = (const float*)d_in[13];
    const float* W_g1   = (const float*)d_in[14];
    const float* b_g1   = (const float*)d_in[15];
    const float* W_g2   = (const float*)d_in[16];
    const float* b_g2   = (const float*)d_in[17];

    char* ws = (char*)d_ws;
    u16* inp  = (u16*)(ws + 0);            // 128 MB (h1 pre-relu input term)
    u16* hA   = (u16*)(ws + 128000000);    // 128 MB; reused as ah
    u16* hB   = (u16*)(ws + 256000000);    // 128 MB
    u16* amsg = (u16*)(ws + 384000000);    // 64 MB
    u16* wt_i = (u16*)(ws + 448000000);    // 320x160
    u16* wt_h = (u16*)(ws + 448200000);    // 320x320
    u16* wt_o = (u16*)(ws + 448500000);    // 320x448
    u16* wt_n = (u16*)(ws + 448800000);    // 192x320
    u16* wt_e = (u16*)(ws + 449000000);    // 64x320
    float* gemb = (float*)(ws + 449300000); // 2000x320 f32
    float* gh   = (float*)(ws + 452000000); // 2000x320 f32

    float* out_node  = (float*)d_out;
    float* out_edge  = out_node + (size_t)N_ATOMS * ATOM_FDIM;
    float* out_graph = out_node + 14700000;

    dim3 blk(256);

    // pack weights (bf16, transposed, zero-padded)
    k_pack_wt<<<(320 * 160 + 255) / 256, blk, 0, stream>>>(W_i, wt_i, BOND_FDIM, HIDDEN, 160, 320);
    k_pack_wt<<<(320 * 320 + 255) / 256, blk, 0, stream>>>(W_h, wt_h, HIDDEN, HIDDEN, 320, 320);
    k_pack_wo<<<(320 * CATP + 255) / 256, blk, 0, stream>>>(W_o, wt_o);
    k_pack_wt<<<(192 * 320 + 255) / 256, blk, 0, stream>>>(W_node, wt_n, HIDDEN, ATOM_FDIM, 320, 192);
    k_pack_wt<<<(64 * 320 + 255) / 256, blk, 0, stream>>>(W_edge, wt_e, HIDDEN, 14, 320, 64);

    const int gB32 = (N_BONDS + 31) / 32;   // 6250
    const int gA32 = (N_ATOMS + 31) / 32;   // 3125
    const int gE128 = (N_EDGES + 127) / 128; // 782
    const int gAg = (N_ATOMS * 40 + 255) / 256;

    // inp = f_bonds @ W_i  (fused f32->bf16 in fragment load; pre-relu stored)
    k_gemm<1, 1, 5, 5, 0><<<gB32, blk, 0, stream>>>(
        f_bonds, nullptr, nullptr, nullptr, nullptr, BOND_FDIM, N_BONDS,
        wt_i, 160, 0, nullptr, 0, nullptr, inp, nullptr);

    // depth loop: h_{d+1} = inp + (amsg[b2a] - relu(h_d[b2revb])) @ W_h
    const u16* hcur = inp;
    u16* houts[2] = { hA, hB };
    for (int d = 0; d < 2; ++d) {
        k_aggregate<<<gAg, blk, 0, stream>>>(hcur, a2b, amsg);
        k_gemm<2, 2, 10, 5, 0><<<gB32, blk, 0, stream>>>(
            nullptr, amsg, hcur, b2a, b2revb, 0, N_BONDS,
            wt_h, 320, 0, nullptr, 0, nullptr, houts[d], inp);
        hcur = houts[d];
    }

    // final aggregate + fused-concat W_o -> atom_hiddens (relu'd, bf16)
    k_aggregate<<<gAg, blk, 0, stream>>>(hcur, a2b, amsg);
    u16* ah = hA; // free after d=1 GEMM consumed it
    k_gemm<3, 3, 14, 5, 0><<<gA32, blk, 0, stream>>>(
        f_atoms, amsg, nullptr, nullptr, nullptr, 0, N_ATOMS,
        wt_o, CATP, HIDDEN, nullptr, 0, b_o, ah, nullptr);

    // node head (cols 0..191 computed, 0..132 stored)
    k_gemm<0, 0, 10, 3, 0><<<gA32, blk, 0, stream>>>(
        nullptr, ah, nullptr, nullptr, nullptr, HP, N_ATOMS,
        wt_n, 320, ATOM_FDIM, out_node, ATOM_FDIM, b_node, nullptr, nullptr);

    // edge head (fused h_avg gather; waves tile M, 1 col-frag)
    k_gemm<4, 0, 10, 1, 1><<<gE128, blk, 0, stream>>>(
        nullptr, ah, nullptr, b2a, b2revb, 0, N_EDGES,
        wt_e, 320, 14, out_edge, 14, b_edge, nullptr, nullptr);

    // graph head
    k_segsum<<<N_MOLS, 320, 0, stream>>>(ah, gidx, gemb);
    k_g1<<<N_MOLS, 320, 0, stream>>>(gemb, W_g1, b_g1, gh);
    k_g2<<<N_MOLS, 64, 0, stream>>>(gh, W_g2, b_g2, out_graph);
}

// Round 5
// 1276.139 us; speedup vs baseline: 1.4191x; 1.2169x over previous
//
#include <hip/hip_runtime.h>

typedef unsigned short u16;
typedef unsigned int u32;

#define N_ATOMS 100000
#define N_BONDS 200000
#define N_EDGES 100000
#define HIDDEN 300
#define HP 320
#define ATOM_FDIM 133
#define BOND_FDIM 147
#define CATP 448
#define N_MOLS 2000

typedef __bf16 bf16x8 __attribute__((ext_vector_type(8)));
typedef float f32x4 __attribute__((ext_vector_type(4)));

__device__ __forceinline__ u16 f2bf(float f) {
    union { float f; u32 u; } x; x.f = f;
    u32 u = x.u;
    u32 r = u + 0x7fffu + ((u >> 16) & 1u);
    return (u16)(r >> 16);
}
__device__ __forceinline__ float bf2f(u16 h) {
    union { u32 u; float f; } x; x.u = ((u32)h) << 16;
    return x.f;
}

union U8 { uint4 v; u16 h[8]; };

// ============ LDS-staged fused GEMM: stage A once, ONE barrier, then ============
// ============ a barrier-free k-loop (ds_read A + global B + MFMA).   ============
// Block: 32 rows x 320 cols (full N), 256 threads = 4 waves, wave w = cols w*80.
// A staged into LDS with per-row XOR chunk swizzle (bank-spread for b128 reads).
//  ASRC 1: f32 rows (f_bonds), width lda, zero-pad
//  ASRC 2: delta = amsg[i1[r]] - relu(h[i2[r]])
//  ASRC 3: cat   = [amsg[r] (300, cols 300..303 are zeros) | f32 f_atoms (133) | 0]
// Epilogue EP: 1: O1=bf16(acc); 2: O1=bf16(acc+inp_in); 3: O1=bf16(relu(acc+bias))
template<int ASRC, int EP, int KSTEPS>
__global__ __launch_bounds__(256) void k_gemm_lds(
    const float* __restrict__ fsrc, const u16* __restrict__ src16,
    const u16* __restrict__ src16b, const int* __restrict__ i1,
    const int* __restrict__ i2, int lda, int M,
    const u16* __restrict__ Bt, int ldb,
    int Nout, float* __restrict__ Cf, int ldc,
    const float* __restrict__ bias, u16* __restrict__ O1,
    const u16* __restrict__ inp_in)
{
    constexpr int CHPR = KSTEPS * 4;                 // 16B chunks per row
    constexpr int MASK = (CHPR % 8 == 0) ? 7 : 3;    // XOR swizzle domain
    __shared__ __align__(16) u16 As[32 * CHPR * 8];

    const int tid = threadIdx.x;
    const int row0 = blockIdx.x * 32;

    // ---- stage A tile (once) ----
    constexpr int TOT = 32 * CHPR;
    constexpr int ITER = (TOT + 255) / 256;
#pragma unroll
    for (int it = 0; it < ITER; it++) {
        int ch = tid + it * 256;
        if (TOT % 256 != 0 && ch >= TOT) break;
        int r = ch / CHPR, c = ch - r * CHPR;
        int row = row0 + r; if (row >= M) row = M - 1;
        U8 u;
        if constexpr (ASRC == 1) {
            size_t fb = (size_t)row * lda;
#pragma unroll
            for (int e = 0; e < 8; e++) {
                int col = c * 8 + e;
                u.h[e] = (col < lda) ? f2bf(fsrc[fb + col]) : (u16)0;
            }
        } else if constexpr (ASRC == 2) {
            U8 x, y;
            x.v = *(const uint4*)(src16  + (size_t)i1[row] * HP + c * 8);
            y.v = *(const uint4*)(src16b + (size_t)i2[row] * HP + c * 8);
#pragma unroll
            for (int e = 0; e < 8; e++)
                u.h[e] = f2bf(bf2f(x.h[e]) - fmaxf(bf2f(y.h[e]), 0.f));
        } else {
            if (c < 38) {                 // cols 0..303 from amsg (300..303 are zeros)
                u.v = *(const uint4*)(src16 + (size_t)row * HP + c * 8);
            } else {
                size_t fb = (size_t)row * ATOM_FDIM;
#pragma unroll
                for (int e = 0; e < 8; e++) {
                    int col = c * 8 + e - 304;     // f_atoms region
                    u.h[e] = (col >= 0 && col < ATOM_FDIM) ? f2bf(fsrc[fb + col]) : (u16)0;
                }
            }
        }
        *(uint4*)&As[(size_t)(r * CHPR + (c ^ (r & MASK))) * 8] = u.v;
    }
    __syncthreads();

    // ---- barrier-free MFMA loop ----
    const int lane = tid & 63;
    const int w = tid >> 6;
    const int ncol0 = w * 80;
    const int lrow = lane & 15;
    const int g = lane >> 4;
    const int lkb = g * 8;
    const int xr = lrow & MASK;          // (lrow+16)&MASK == lrow&MASK

    const u16* pb[5];
#pragma unroll
    for (int n = 0; n < 5; n++)
        pb[n] = Bt + (size_t)(ncol0 + n * 16 + lrow) * ldb + lkb;

    f32x4 acc[2][5] = {};

#pragma unroll
    for (int ks = 0; ks < KSTEPS; ks++) {
        const int ck = ks * 4 + g;
        const int sw = ck ^ xr;
        bf16x8 a0 = *(const bf16x8*)&As[(size_t)(lrow * CHPR + sw) * 8];
        bf16x8 a1 = *(const bf16x8*)&As[(size_t)((lrow + 16) * CHPR + sw) * 8];
        bf16x8 bfr[5];
#pragma unroll
        for (int n = 0; n < 5; n++) bfr[n] = *(const bf16x8*)(pb[n] + ks * 32);
#pragma unroll
        for (int n = 0; n < 5; n++) {
            acc[0][n] = __builtin_amdgcn_mfma_f32_16x16x32_bf16(a0, bfr[n], acc[0][n], 0, 0, 0);
            acc[1][n] = __builtin_amdgcn_mfma_f32_16x16x32_bf16(a1, bfr[n], acc[1][n], 0, 0, 0);
        }
    }

    const int orow = g * 4;
    const int ocol = lrow;
#pragma unroll
    for (int m = 0; m < 2; m++) {
#pragma unroll
        for (int n = 0; n < 5; n++) {
#pragma unroll
            for (int q = 0; q < 4; q++) {
                int grow = row0 + m * 16 + orow + q;
                int gcol = ncol0 + n * 16 + ocol;
                float v = acc[m][n][q];
                if constexpr (EP == 1) {
                    if (grow < M) O1[(size_t)grow * HP + gcol] = f2bf(v);
                } else if constexpr (EP == 2) {
                    if (grow < M) {
                        float x = v + bf2f(inp_in[(size_t)grow * HP + gcol]);
                        O1[(size_t)grow * HP + gcol] = f2bf(x);
                    }
                } else {
                    if (grow < M) {
                        float x = v + (gcol < Nout ? bias[gcol] : 0.f);
                        O1[(size_t)grow * HP + gcol] = f2bf(fmaxf(x, 0.f));
                    }
                }
            }
        }
    }
}

// =================== barrier-free direct-from-global MFMA GEMM ===================
// (kept for node head ASRC0 and edge head ASRC4/WAVEM1 — no staging redundancy)
template<int ASRC, int EP, int KSTEPS, int NFW, int WAVEM>
__global__ __launch_bounds__(256) void k_gemm(
    const float* __restrict__ fsrc, const u16* __restrict__ src16,
    const u16* __restrict__ src16b, const int* __restrict__ i1,
    const int* __restrict__ i2, int lda, int M,
    const u16* __restrict__ Bt, int ldb,
    int Nout, float* __restrict__ Cf, int ldc,
    const float* __restrict__ bias, u16* __restrict__ O1,
    const u16* __restrict__ inp_in)
{
    const int tid = threadIdx.x;
    const int lane = tid & 63;
    const int w = tid >> 6;
    const int lrow = lane & 15;
    const int lkb = (lane >> 4) * 8;

    int row0, ncol0;
    if constexpr (WAVEM) { row0 = blockIdx.x * 128 + w * 32; ncol0 = 0; }
    else                 { row0 = blockIdx.x * 32;           ncol0 = w * (NFW * 16); }

    const u16* pa[2] = {nullptr, nullptr};
    const u16* pa2[2] = {nullptr, nullptr};
#pragma unroll
    for (int m = 0; m < 2; m++) {
        int r = row0 + m * 16 + lrow; if (r >= M) r = M - 1;
        if constexpr (ASRC == 0) pa[m] = src16 + (size_t)r * lda + lkb;
        if constexpr (ASRC == 4) {
            int e = 2 * r;
            pa[m]  = src16 + (size_t)i1[e] * HP + lkb;
            pa2[m] = src16 + (size_t)i1[i2[e]] * HP + lkb;
        }
    }

    const u16* pb[NFW];
#pragma unroll
    for (int n = 0; n < NFW; n++)
        pb[n] = Bt + (size_t)(ncol0 + n * 16 + lrow) * ldb + lkb;

    auto loadAfrag = [&](int m, int k0) -> bf16x8 {
        U8 u;
        if constexpr (ASRC == 0) {
            u.v = *(const uint4*)(pa[m] + k0);
        } else {
            U8 x, y; x.v = *(const uint4*)(pa[m] + k0); y.v = *(const uint4*)(pa2[m] + k0);
#pragma unroll
            for (int e = 0; e < 8; e++)
                u.h[e] = f2bf(0.5f * (bf2f(x.h[e]) + bf2f(y.h[e])));
        }
        return *(bf16x8*)&u;
    };

    f32x4 acc[2][NFW] = {};

#pragma unroll
    for (int ks = 0; ks < KSTEPS; ks++) {
        const int k0 = ks * 32;
        bf16x8 a0 = loadAfrag(0, k0);
        bf16x8 a1 = loadAfrag(1, k0);
        bf16x8 bfr[NFW];
#pragma unroll
        for (int n = 0; n < NFW; n++) bfr[n] = *(const bf16x8*)(pb[n] + k0);
#pragma unroll
        for (int n = 0; n < NFW; n++) {
            acc[0][n] = __builtin_amdgcn_mfma_f32_16x16x32_bf16(a0, bfr[n], acc[0][n], 0, 0, 0);
            acc[1][n] = __builtin_amdgcn_mfma_f32_16x16x32_bf16(a1, bfr[n], acc[1][n], 0, 0, 0);
        }
    }

    const int orow = (lane >> 4) * 4;
    const int ocol = lane & 15;
#pragma unroll
    for (int m = 0; m < 2; m++) {
#pragma unroll
        for (int n = 0; n < NFW; n++) {
#pragma unroll
            for (int q = 0; q < 4; q++) {
                int grow = row0 + m * 16 + orow + q;
                int gcol = ncol0 + n * 16 + ocol;
                float v = acc[m][n][q];
                if constexpr (EP == 0) {
                    if (grow < M && gcol < Nout)
                        Cf[(size_t)grow * ldc + gcol] = v + bias[gcol];
                } else {
                    if (grow < M) O1[(size_t)grow * HP + gcol] = f2bf(v);
                }
            }
        }
    }
}

// ---------------- weight pack: Bt[n][k] = W[k][n], bf16, zero-padded ----------------
__global__ void k_pack_wt(const float* __restrict__ W, u16* __restrict__ Bt,
                          int K, int N, int Kp, int Np)
{
    int idx = blockIdx.x * 256 + threadIdx.x;
    if (idx >= Np * Kp) return;
    int n = idx / Kp, k = idx - n * Kp;
    Bt[idx] = (n < N && k < K) ? f2bf(W[(size_t)k * N + n]) : (u16)0;
}

// W_o pack with the [amsg(300) | pad4 | f_atoms(133) | pad] column reorder
__global__ void k_pack_wo(const float* __restrict__ W, u16* __restrict__ Bt)
{
    int idx = blockIdx.x * 256 + threadIdx.x;
    if (idx >= 320 * CATP) return;
    int n = idx / CATP, k = idx - n * CATP;
    float v = 0.f;
    if (n < HIDDEN) {
        if (k < HIDDEN) v = W[(size_t)(ATOM_FDIM + k) * HIDDEN + n];
        else if (k >= 304 && k < 304 + ATOM_FDIM) v = W[(size_t)(k - 304) * HIDDEN + n];
    }
    Bt[idx] = f2bf(v);
}

// ---------------- a_msg[a] = sum_j relu(h[a2b[a][j]]) ----------------
__global__ __launch_bounds__(256) void k_aggregate(const u16* __restrict__ h,
    const int* __restrict__ a2b, u16* __restrict__ amsg)
{
    int idx = blockIdx.x * 256 + threadIdx.x;
    if (idx >= N_ATOMS * 40) return;
    int a = idx / 40, c = (idx - a * 40) * 8;
    float s[8] = {};
#pragma unroll
    for (int j = 0; j < 6; j++) {
        int b = a2b[a * 6 + j];
        U8 u; u.v = *(const uint4*)&h[(size_t)b * HP + c];
#pragma unroll
        for (int i = 0; i < 8; i++) s[i] += fmaxf(bf2f(u.h[i]), 0.f);
    }
    U8 o;
#pragma unroll
    for (int i = 0; i < 8; i++) o.h[i] = f2bf(s[i]);
    *(uint4*)&amsg[(size_t)a * HP + c] = o.v;
}

// ---------------- per-molecule segment sum (graph_idx sorted) ----------------
__device__ __forceinline__ int lower_bound_i(const int* a, int n, int v) {
    int lo = 0, hi = n;
    while (lo < hi) { int mid = (lo + hi) >> 1; if (a[mid] < v) lo = mid + 1; else hi = mid; }
    return lo;
}
__global__ __launch_bounds__(320) void k_segsum(const u16* __restrict__ ah,
    const int* __restrict__ gidx, float* __restrict__ gemb)
{
    int g = blockIdx.x;
    int c = threadIdx.x;
    int s = lower_bound_i(gidx, N_ATOMS, g);
    int e = lower_bound_i(gidx, N_ATOMS, g + 1);
    float sum = 0.f;
    for (int a = s; a < e; a++) sum += bf2f(ah[(size_t)a * HP + c]);
    gemb[(size_t)g * HP + c] = sum;
}

// ---------------- graph head (fp32) ----------------
__global__ __launch_bounds__(320) void k_g1(const float* __restrict__ gemb,
    const float* __restrict__ W, const float* __restrict__ b, float* __restrict__ gh)
{
    int g = blockIdx.x, j = threadIdx.x;
    float acc = 0.f;
    if (j < HIDDEN) {
        acc = b[j];
        for (int k = 0; k < HIDDEN; k++)
            acc = fmaf(gemb[(size_t)g * HP + k], W[(size_t)k * HIDDEN + j], acc);
        acc = fmaxf(acc, 0.f);
    }
    gh[(size_t)g * HP + j] = (j < HIDDEN) ? acc : 0.f;
}
__global__ __launch_bounds__(64) void k_g2(const float* __restrict__ gh,
    const float* __restrict__ W, const float* __restrict__ b, float* __restrict__ out)
{
    int g = blockIdx.x, l = threadIdx.x;
    float acc = 0.f;
    for (int j = l; j < HIDDEN; j += 64) acc += gh[(size_t)g * HP + j] * W[j];
#pragma unroll
    for (int off = 32; off; off >>= 1) acc += __shfl_down(acc, off, 64);
    if (l == 0) out[g] = acc + b[0];
}

extern "C" void kernel_launch(void* const* d_in, const int* in_sizes, int n_in,
                              void* d_out, int out_size, void* d_ws, size_t ws_size,
                              hipStream_t stream)
{
    const float* f_atoms = (const float*)d_in[0];
    const float* f_bonds = (const float*)d_in[1];
    const int* a2b    = (const int*)d_in[2];
    const int* b2a    = (const int*)d_in[3];
    const int* b2revb = (const int*)d_in[4];
    const int* gidx   = (const int*)d_in[5];
    const float* W_i    = (const float*)d_in[6];
    const float* W_h    = (const float*)d_in[7];
    const float* W_o    = (const float*)d_in[8];
    const float* b_o    = (const float*)d_in[9];
    const float* W_node = (const float*)d_in[10];
    const float* b_node = (const float*)d_in[11];
    const float* W_edge = (const float*)d_in[12];
    const float* b_edge = (const float*)d_in[13];
    const float* W_g1   = (const float*)d_in[14];
    const float* b_g1   = (const float*)d_in[15];
    const float* W_g2   = (const float*)d_in[16];
    const float* b_g2   = (const float*)d_in[17];

    char* ws = (char*)d_ws;
    u16* inp  = (u16*)(ws + 0);            // 128 MB (h1 pre-relu input term)
    u16* hA   = (u16*)(ws + 128000000);    // 128 MB; reused as ah
    u16* hB   = (u16*)(ws + 256000000);    // 128 MB
    u16* amsg = (u16*)(ws + 384000000);    // 64 MB
    u16* wt_i = (u16*)(ws + 448000000);    // 320x160
    u16* wt_h = (u16*)(ws + 448200000);    // 320x320
    u16* wt_o = (u16*)(ws + 448500000);    // 320x448
    u16* wt_n = (u16*)(ws + 448800000);    // 192x320
    u16* wt_e = (u16*)(ws + 449000000);    // 64x320
    float* gemb = (float*)(ws + 449300000); // 2000x320 f32
    float* gh   = (float*)(ws + 452000000); // 2000x320 f32

    float* out_node  = (float*)d_out;
    float* out_edge  = out_node + (size_t)N_ATOMS * ATOM_FDIM;
    float* out_graph = out_node + 14700000;

    dim3 blk(256);

    // pack weights (bf16, transposed, zero-padded)
    k_pack_wt<<<(320 * 160 + 255) / 256, blk, 0, stream>>>(W_i, wt_i, BOND_FDIM, HIDDEN, 160, 320);
    k_pack_wt<<<(320 * 320 + 255) / 256, blk, 0, stream>>>(W_h, wt_h, HIDDEN, HIDDEN, 320, 320);
    k_pack_wo<<<(320 * CATP + 255) / 256, blk, 0, stream>>>(W_o, wt_o);
    k_pack_wt<<<(192 * 320 + 255) / 256, blk, 0, stream>>>(W_node, wt_n, HIDDEN, ATOM_FDIM, 320, 192);
    k_pack_wt<<<(64 * 320 + 255) / 256, blk, 0, stream>>>(W_edge, wt_e, HIDDEN, 14, 320, 64);

    const int gB32 = (N_BONDS + 31) / 32;    // 6250
    const int gA32 = (N_ATOMS + 31) / 32;    // 3125
    const int gE128 = (N_EDGES + 127) / 128; // 782
    const int gAg = (N_ATOMS * 40 + 255) / 256;

    // inp = f_bonds @ W_i  (f32->bf16 staged to LDS once; pre-relu stored)
    k_gemm_lds<1, 1, 5><<<gB32, blk, 0, stream>>>(
        f_bonds, nullptr, nullptr, nullptr, nullptr, BOND_FDIM, N_BONDS,
        wt_i, 160, 0, nullptr, 0, nullptr, inp, nullptr);

    // depth loop: h_{d+1} = inp + (amsg[b2a] - relu(h_d[b2revb])) @ W_h
    const u16* hcur = inp;
    u16* houts[2] = { hA, hB };
    for (int d = 0; d < 2; ++d) {
        k_aggregate<<<gAg, blk, 0, stream>>>(hcur, a2b, amsg);
        k_gemm_lds<2, 2, 10><<<gB32, blk, 0, stream>>>(
            nullptr, amsg, hcur, b2a, b2revb, 0, N_BONDS,
            wt_h, 320, 0, nullptr, 0, nullptr, houts[d], inp);
        hcur = houts[d];
    }

    // final aggregate + fused-concat W_o -> atom_hiddens (relu'd, bf16)
    k_aggregate<<<gAg, blk, 0, stream>>>(hcur, a2b, amsg);
    u16* ah = hA; // free after d=1 GEMM consumed it
    k_gemm_lds<3, 3, 14><<<gA32, blk, 0, stream>>>(
        f_atoms, amsg, nullptr, nullptr, nullptr, 0, N_ATOMS,
        wt_o, CATP, HIDDEN, nullptr, 0, b_o, ah, nullptr);

    // node head (linear A, direct; cols 0..191 computed, 0..132 stored)
    k_gemm<0, 0, 10, 3, 0><<<gA32, blk, 0, stream>>>(
        nullptr, ah, nullptr, nullptr, nullptr, HP, N_ATOMS,
        wt_n, 320, ATOM_FDIM, out_node, ATOM_FDIM, b_node, nullptr, nullptr);

    // edge head (fused h_avg gather; waves tile M, 1 col-frag)
    k_gemm<4, 0, 10, 1, 1><<<gE128, blk, 0, stream>>>(
        nullptr, ah, nullptr, b2a, b2revb, 0, N_EDGES,
        wt_e, 320, 14, out_edge, 14, b_edge, nullptr, nullptr);

    // graph head
    k_segsum<<<N_MOLS, 320, 0, stream>>>(ah, gidx, gemb);
    k_g1<<<N_MOLS, 320, 0, stream>>>(gemb, W_g1, b_g1, gh);
    k_g2<<<N_MOLS, 64, 0, stream>>>(gh, W_g2, b_g2, out_graph);
}

// Round 6
// 1149.912 us; speedup vs baseline: 1.5748x; 1.1098x over previous
//
#include <hip/hip_runtime.h>

typedef unsigned short u16;
typedef unsigned int u32;

#define N_ATOMS 100000
#define N_BONDS 200000
#define N_EDGES 100000
#define HIDDEN 300
#define HP 320
#define ATOM_FDIM 133
#define BOND_FDIM 147
#define CATP 448
#define N_MOLS 2000

typedef __bf16 bf16x8 __attribute__((ext_vector_type(8)));
typedef float f32x4 __attribute__((ext_vector_type(4)));

__device__ __forceinline__ u16 f2bf(float f) {
    union { float f; u32 u; } x; x.f = f;
    u32 u = x.u;
    u32 r = u + 0x7fffu + ((u >> 16) & 1u);
    return (u16)(r >> 16);
}
__device__ __forceinline__ float bf2f(u16 h) {
    union { u32 u; float f; } x; x.u = ((u32)h) << 16;
    return x.f;
}

union U8 { uint4 v; u16 h[8]; };
union U4 { uint2 v; u16 h[4]; };

// ============ LDS-staged fused GEMM: stage A once, ONE barrier, then ============
// ============ a barrier-free k-loop (ds_read A + dbuf global B + MFMA) ==========
// Block: 32 rows x 320 cols (full N), 256 threads = 4 waves, wave w = cols w*80.
// MFMA operand-swapped: acc = mfma(B, A, acc) -> lane holds 4 CONSECUTIVE output
// cols (vectorized 8B epilogue stores). M must be a multiple of 32.
//  ASRC 1: f32 rows (f_bonds), width lda, zero-pad
//  ASRC 2: delta = amsg[i1[r]] - relu(h[i2[r]])
//  ASRC 3: cat   = [amsg[r] (300, 300..303 zero) | f32 f_atoms (133) | 0]
// Epilogue EP: 1: O1=bf16(acc); 2: O1=bf16(acc+inp_in); 3: O1=bf16(relu(acc+bias))
template<int ASRC, int EP, int KSTEPS>
__global__ __launch_bounds__(256, 4) void k_gemm_lds(
    const float* __restrict__ fsrc, const u16* __restrict__ src16,
    const u16* __restrict__ src16b, const int* __restrict__ i1,
    const int* __restrict__ i2, int lda, int M,
    const u16* __restrict__ Bt, int ldb,
    int Nout, float* __restrict__ Cf, int ldc,
    const float* __restrict__ bias, u16* __restrict__ O1,
    const u16* __restrict__ inp_in)
{
    constexpr int CHPR = KSTEPS * 4;                 // 16B chunks per row
    constexpr int MASK = (CHPR % 8 == 0) ? 7 : 3;    // XOR swizzle domain
    __shared__ __align__(16) u16 As[32 * CHPR * 8];

    const int tid = threadIdx.x;
    const int row0 = blockIdx.x * 32;

    // ---- stage A tile (once) ----
    constexpr int TOT = 32 * CHPR;
    constexpr int ITER = (TOT + 255) / 256;
#pragma unroll
    for (int it = 0; it < ITER; it++) {
        int ch = tid + it * 256;
        if (TOT % 256 != 0 && ch >= TOT) break;
        int r = ch / CHPR, c = ch - r * CHPR;
        int row = row0 + r; if (row >= M) row = M - 1;
        U8 u;
        if constexpr (ASRC == 1) {
            size_t fb = (size_t)row * lda;
#pragma unroll
            for (int e = 0; e < 8; e++) {
                int col = c * 8 + e;
                u.h[e] = (col < lda) ? f2bf(fsrc[fb + col]) : (u16)0;
            }
        } else if constexpr (ASRC == 2) {
            U8 x, y;
            x.v = *(const uint4*)(src16  + (size_t)i1[row] * HP + c * 8);
            y.v = *(const uint4*)(src16b + (size_t)i2[row] * HP + c * 8);
#pragma unroll
            for (int e = 0; e < 8; e++)
                u.h[e] = f2bf(bf2f(x.h[e]) - fmaxf(bf2f(y.h[e]), 0.f));
        } else {
            if (c < 38) {                 // cols 0..303 from amsg (300..303 zeros)
                u.v = *(const uint4*)(src16 + (size_t)row * HP + c * 8);
            } else {
                size_t fb = (size_t)row * ATOM_FDIM;
#pragma unroll
                for (int e = 0; e < 8; e++) {
                    int col = c * 8 + e - 304;     // f_atoms region
                    u.h[e] = (col >= 0 && col < ATOM_FDIM) ? f2bf(fsrc[fb + col]) : (u16)0;
                }
            }
        }
        *(uint4*)&As[(size_t)(r * CHPR + (c ^ (r & MASK))) * 8] = u.v;
    }
    __syncthreads();

    // ---- barrier-free MFMA loop, B double-buffered in regs ----
    const int lane = tid & 63;
    const int w = tid >> 6;
    const int ncol0 = w * 80;
    const int lrow = lane & 15;
    const int g = lane >> 4;
    const int lkb = g * 8;
    const int xr = lrow & MASK;

    const u16* pb[5];
#pragma unroll
    for (int n = 0; n < 5; n++)
        pb[n] = Bt + (size_t)(ncol0 + n * 16 + lrow) * ldb + lkb;

    f32x4 acc[2][5] = {};
    bf16x8 bcur[5], bnxt[5];
#pragma unroll
    for (int n = 0; n < 5; n++) bcur[n] = *(const bf16x8*)(pb[n]);

#pragma unroll
    for (int ks = 0; ks < KSTEPS; ks++) {
        if (ks + 1 < KSTEPS) {
#pragma unroll
            for (int n = 0; n < 5; n++) bnxt[n] = *(const bf16x8*)(pb[n] + (ks + 1) * 32);
        }
        const int sw = (ks * 4 + g) ^ xr;
        bf16x8 a0 = *(const bf16x8*)&As[(size_t)(lrow * CHPR + sw) * 8];
        bf16x8 a1 = *(const bf16x8*)&As[(size_t)((lrow + 16) * CHPR + sw) * 8];
#pragma unroll
        for (int n = 0; n < 5; n++) {
            // operand-swapped: computes C^T fragments
            acc[0][n] = __builtin_amdgcn_mfma_f32_16x16x32_bf16(bcur[n], a0, acc[0][n], 0, 0, 0);
            acc[1][n] = __builtin_amdgcn_mfma_f32_16x16x32_bf16(bcur[n], a1, acc[1][n], 0, 0, 0);
        }
#pragma unroll
        for (int n = 0; n < 5; n++) bcur[n] = bnxt[n];
    }

    // ---- vectorized epilogue: lane owns rows row0+m*16+lrow, cols ncol0+n*16+g*4+q ----
#pragma unroll
    for (int m = 0; m < 2; m++) {
        const int row = row0 + m * 16 + lrow;   // M % 32 == 0 -> always valid
#pragma unroll
        for (int n = 0; n < 5; n++) {
            const int colb = ncol0 + n * 16 + g * 4;
            U4 o;
            if constexpr (EP == 1) {
#pragma unroll
                for (int q = 0; q < 4; q++) o.h[q] = f2bf(acc[m][n][q]);
            } else if constexpr (EP == 2) {
                U4 ii; ii.v = *(const uint2*)&inp_in[(size_t)row * HP + colb];
#pragma unroll
                for (int q = 0; q < 4; q++) o.h[q] = f2bf(acc[m][n][q] + bf2f(ii.h[q]));
            } else {
#pragma unroll
                for (int q = 0; q < 4; q++) {
                    float x = acc[m][n][q] + ((colb + q) < Nout ? bias[colb + q] : 0.f);
                    o.h[q] = f2bf(fmaxf(x, 0.f));
                }
            }
            *(uint2*)&O1[(size_t)row * HP + colb] = o.v;
        }
    }
}

// =================== barrier-free direct-from-global MFMA GEMM ===================
// (node head ASRC0 and edge head ASRC4/WAVEM1 — no staging redundancy)
template<int ASRC, int EP, int KSTEPS, int NFW, int WAVEM>
__global__ __launch_bounds__(256) void k_gemm(
    const float* __restrict__ fsrc, const u16* __restrict__ src16,
    const u16* __restrict__ src16b, const int* __restrict__ i1,
    const int* __restrict__ i2, int lda, int M,
    const u16* __restrict__ Bt, int ldb,
    int Nout, float* __restrict__ Cf, int ldc,
    const float* __restrict__ bias, u16* __restrict__ O1,
    const u16* __restrict__ inp_in)
{
    const int tid = threadIdx.x;
    const int lane = tid & 63;
    const int w = tid >> 6;
    const int lrow = lane & 15;
    const int lkb = (lane >> 4) * 8;

    int row0, ncol0;
    if constexpr (WAVEM) { row0 = blockIdx.x * 128 + w * 32; ncol0 = 0; }
    else                 { row0 = blockIdx.x * 32;           ncol0 = w * (NFW * 16); }

    const u16* pa[2] = {nullptr, nullptr};
    const u16* pa2[2] = {nullptr, nullptr};
#pragma unroll
    for (int m = 0; m < 2; m++) {
        int r = row0 + m * 16 + lrow; if (r >= M) r = M - 1;
        if constexpr (ASRC == 0) pa[m] = src16 + (size_t)r * lda + lkb;
        if constexpr (ASRC == 4) {
            int e = 2 * r;
            pa[m]  = src16 + (size_t)i1[e] * HP + lkb;
            pa2[m] = src16 + (size_t)i1[i2[e]] * HP + lkb;
        }
    }

    const u16* pb[NFW];
#pragma unroll
    for (int n = 0; n < NFW; n++)
        pb[n] = Bt + (size_t)(ncol0 + n * 16 + lrow) * ldb + lkb;

    auto loadAfrag = [&](int m, int k0) -> bf16x8 {
        U8 u;
        if constexpr (ASRC == 0) {
            u.v = *(const uint4*)(pa[m] + k0);
        } else {
            U8 x, y; x.v = *(const uint4*)(pa[m] + k0); y.v = *(const uint4*)(pa2[m] + k0);
#pragma unroll
            for (int e = 0; e < 8; e++)
                u.h[e] = f2bf(0.5f * (bf2f(x.h[e]) + bf2f(y.h[e])));
        }
        return *(bf16x8*)&u;
    };

    f32x4 acc[2][NFW] = {};

#pragma unroll
    for (int ks = 0; ks < KSTEPS; ks++) {
        const int k0 = ks * 32;
        bf16x8 a0 = loadAfrag(0, k0);
        bf16x8 a1 = loadAfrag(1, k0);
        bf16x8 bfr[NFW];
#pragma unroll
        for (int n = 0; n < NFW; n++) bfr[n] = *(const bf16x8*)(pb[n] + k0);
#pragma unroll
        for (int n = 0; n < NFW; n++) {
            acc[0][n] = __builtin_amdgcn_mfma_f32_16x16x32_bf16(a0, bfr[n], acc[0][n], 0, 0, 0);
            acc[1][n] = __builtin_amdgcn_mfma_f32_16x16x32_bf16(a1, bfr[n], acc[1][n], 0, 0, 0);
        }
    }

    const int orow = (lane >> 4) * 4;
    const int ocol = lane & 15;
#pragma unroll
    for (int m = 0; m < 2; m++) {
#pragma unroll
        for (int n = 0; n < NFW; n++) {
#pragma unroll
            for (int q = 0; q < 4; q++) {
                int grow = row0 + m * 16 + orow + q;
                int gcol = ncol0 + n * 16 + ocol;
                float v = acc[m][n][q];
                if constexpr (EP == 0) {
                    if (grow < M && gcol < Nout)
                        Cf[(size_t)grow * ldc + gcol] = v + bias[gcol];
                } else {
                    if (grow < M) O1[(size_t)grow * HP + gcol] = f2bf(v);
                }
            }
        }
    }
}

// ---------------- weight pack: Bt[n][k] = W[k][n], bf16, zero-padded ----------------
__global__ void k_pack_wt(const float* __restrict__ W, u16* __restrict__ Bt,
                          int K, int N, int Kp, int Np)
{
    int idx = blockIdx.x * 256 + threadIdx.x;
    if (idx >= Np * Kp) return;
    int n = idx / Kp, k = idx - n * Kp;
    Bt[idx] = (n < N && k < K) ? f2bf(W[(size_t)k * N + n]) : (u16)0;
}

// W_o pack with the [amsg(300) | pad4 | f_atoms(133) | pad] column reorder
__global__ void k_pack_wo(const float* __restrict__ W, u16* __restrict__ Bt)
{
    int idx = blockIdx.x * 256 + threadIdx.x;
    if (idx >= 320 * CATP) return;
    int n = idx / CATP, k = idx - n * CATP;
    float v = 0.f;
    if (n < HIDDEN) {
        if (k < HIDDEN) v = W[(size_t)(ATOM_FDIM + k) * HIDDEN + n];
        else if (k >= 304 && k < 304 + ATOM_FDIM) v = W[(size_t)(k - 304) * HIDDEN + n];
    }
    Bt[idx] = f2bf(v);
}

// ---------------- a_msg[a] = sum_j relu(h[a2b[a][j]]) ----------------
__global__ __launch_bounds__(256) void k_aggregate(const u16* __restrict__ h,
    const int* __restrict__ a2b, u16* __restrict__ amsg)
{
    int idx = blockIdx.x * 256 + threadIdx.x;
    if (idx >= N_ATOMS * 40) return;
    int a = idx / 40, c = (idx - a * 40) * 8;
    float s[8] = {};
#pragma unroll
    for (int j = 0; j < 6; j++) {
        int b = a2b[a * 6 + j];
        U8 u; u.v = *(const uint4*)&h[(size_t)b * HP + c];
#pragma unroll
        for (int i = 0; i < 8; i++) s[i] += fmaxf(bf2f(u.h[i]), 0.f);
    }
    U8 o;
#pragma unroll
    for (int i = 0; i < 8; i++) o.h[i] = f2bf(s[i]);
    *(uint4*)&amsg[(size_t)a * HP + c] = o.v;
}

// ---------------- per-molecule segment sum (graph_idx sorted) ----------------
__device__ __forceinline__ int lower_bound_i(const int* a, int n, int v) {
    int lo = 0, hi = n;
    while (lo < hi) { int mid = (lo + hi) >> 1; if (a[mid] < v) lo = mid + 1; else hi = mid; }
    return lo;
}
__global__ __launch_bounds__(320) void k_segsum(const u16* __restrict__ ah,
    const int* __restrict__ gidx, float* __restrict__ gemb)
{
    int g = blockIdx.x;
    int c = threadIdx.x;
    int s = lower_bound_i(gidx, N_ATOMS, g);
    int e = lower_bound_i(gidx, N_ATOMS, g + 1);
    float sum = 0.f;
    for (int a = s; a < e; a++) sum += bf2f(ah[(size_t)a * HP + c]);
    gemb[(size_t)g * HP + c] = sum;
}

// ---------------- graph head (fp32) ----------------
__global__ __launch_bounds__(320) void k_g1(const float* __restrict__ gemb,
    const float* __restrict__ W, const float* __restrict__ b, float* __restrict__ gh)
{
    int g = blockIdx.x, j = threadIdx.x;
    float acc = 0.f;
    if (j < HIDDEN) {
        acc = b[j];
        for (int k = 0; k < HIDDEN; k++)
            acc = fmaf(gemb[(size_t)g * HP + k], W[(size_t)k * HIDDEN + j], acc);
        acc = fmaxf(acc, 0.f);
    }
    gh[(size_t)g * HP + j] = (j < HIDDEN) ? acc : 0.f;
}
__global__ __launch_bounds__(64) void k_g2(const float* __restrict__ gh,
    const float* __restrict__ W, const float* __restrict__ b, float* __restrict__ out)
{
    int g = blockIdx.x, l = threadIdx.x;
    float acc = 0.f;
    for (int j = l; j < HIDDEN; j += 64) acc += gh[(size_t)g * HP + j] * W[j];
#pragma unroll
    for (int off = 32; off; off >>= 1) acc += __shfl_down(acc, off, 64);
    if (l == 0) out[g] = acc + b[0];
}

extern "C" void kernel_launch(void* const* d_in, const int* in_sizes, int n_in,
                              void* d_out, int out_size, void* d_ws, size_t ws_size,
                              hipStream_t stream)
{
    const float* f_atoms = (const float*)d_in[0];
    const float* f_bonds = (const float*)d_in[1];
    const int* a2b    = (const int*)d_in[2];
    const int* b2a    = (const int*)d_in[3];
    const int* b2revb = (const int*)d_in[4];
    const int* gidx   = (const int*)d_in[5];
    const float* W_i    = (const float*)d_in[6];
    const float* W_h    = (const float*)d_in[7];
    const float* W_o    = (const float*)d_in[8];
    const float* b_o    = (const float*)d_in[9];
    const float* W_node = (const float*)d_in[10];
    const float* b_node = (const float*)d_in[11];
    const float* W_edge = (const float*)d_in[12];
    const float* b_edge = (const float*)d_in[13];
    const float* W_g1   = (const float*)d_in[14];
    const float* b_g1   = (const float*)d_in[15];
    const float* W_g2   = (const float*)d_in[16];
    const float* b_g2   = (const float*)d_in[17];

    char* ws = (char*)d_ws;
    u16* inp  = (u16*)(ws + 0);            // 128 MB (h1 pre-relu input term)
    u16* hA   = (u16*)(ws + 128000000);    // 128 MB; reused as ah
    u16* hB   = (u16*)(ws + 256000000);    // 128 MB
    u16* amsg = (u16*)(ws + 384000000);    // 64 MB
    u16* wt_i = (u16*)(ws + 448000000);    // 320x160
    u16* wt_h = (u16*)(ws + 448200000);    // 320x320
    u16* wt_o = (u16*)(ws + 448500000);    // 320x448
    u16* wt_n = (u16*)(ws + 448800000);    // 192x320
    u16* wt_e = (u16*)(ws + 449000000);    // 64x320
    float* gemb = (float*)(ws + 449300000); // 2000x320 f32
    float* gh   = (float*)(ws + 452000000); // 2000x320 f32

    float* out_node  = (float*)d_out;
    float* out_edge  = out_node + (size_t)N_ATOMS * ATOM_FDIM;
    float* out_graph = out_node + 14700000;

    dim3 blk(256);

    // pack weights (bf16, transposed, zero-padded)
    k_pack_wt<<<(320 * 160 + 255) / 256, blk, 0, stream>>>(W_i, wt_i, BOND_FDIM, HIDDEN, 160, 320);
    k_pack_wt<<<(320 * 320 + 255) / 256, blk, 0, stream>>>(W_h, wt_h, HIDDEN, HIDDEN, 320, 320);
    k_pack_wo<<<(320 * CATP + 255) / 256, blk, 0, stream>>>(W_o, wt_o);
    k_pack_wt<<<(192 * 320 + 255) / 256, blk, 0, stream>>>(W_node, wt_n, HIDDEN, ATOM_FDIM, 320, 192);
    k_pack_wt<<<(64 * 320 + 255) / 256, blk, 0, stream>>>(W_edge, wt_e, HIDDEN, 14, 320, 64);

    const int gB32 = (N_BONDS + 31) / 32;    // 6250
    const int gA32 = (N_ATOMS + 31) / 32;    // 3125
    const int gE128 = (N_EDGES + 127) / 128; // 782
    const int gAg = (N_ATOMS * 40 + 255) / 256;

    // inp = f_bonds @ W_i  (f32->bf16 staged to LDS once; pre-relu stored)
    k_gemm_lds<1, 1, 5><<<gB32, blk, 0, stream>>>(
        f_bonds, nullptr, nullptr, nullptr, nullptr, BOND_FDIM, N_BONDS,
        wt_i, 160, 0, nullptr, 0, nullptr, inp, nullptr);

    // depth loop: h_{d+1} = inp + (amsg[b2a] - relu(h_d[b2revb])) @ W_h
    const u16* hcur = inp;
    u16* houts[2] = { hA, hB };
    for (int d = 0; d < 2; ++d) {
        k_aggregate<<<gAg, blk, 0, stream>>>(hcur, a2b, amsg);
        k_gemm_lds<2, 2, 10><<<gB32, blk, 0, stream>>>(
            nullptr, amsg, hcur, b2a, b2revb, 0, N_BONDS,
            wt_h, 320, 0, nullptr, 0, nullptr, houts[d], inp);
        hcur = houts[d];
    }

    // final aggregate + fused-concat W_o -> atom_hiddens (relu'd, bf16)
    k_aggregate<<<gAg, blk, 0, stream>>>(hcur, a2b, amsg);
    u16* ah = hA; // free after d=1 GEMM consumed it
    k_gemm_lds<3, 3, 14><<<gA32, blk, 0, stream>>>(
        f_atoms, amsg, nullptr, nullptr, nullptr, 0, N_ATOMS,
        wt_o, CATP, HIDDEN, nullptr, 0, b_o, ah, nullptr);

    // node head (linear A, direct; cols 0..191 computed, 0..132 stored)
    k_gemm<0, 0, 10, 3, 0><<<gA32, blk, 0, stream>>>(
        nullptr, ah, nullptr, nullptr, nullptr, HP, N_ATOMS,
        wt_n, 320, ATOM_FDIM, out_node, ATOM_FDIM, b_node, nullptr, nullptr);

    // edge head (fused h_avg gather; waves tile M, 1 col-frag)
    k_gemm<4, 0, 10, 1, 1><<<gE128, blk, 0, stream>>>(
        nullptr, ah, nullptr, b2a, b2revb, 0, N_EDGES,
        wt_e, 320, 14, out_edge, 14, b_edge, nullptr, nullptr);

    // graph head
    k_segsum<<<N_MOLS, 320, 0, stream>>>(ah, gidx, gemb);
    k_g1<<<N_MOLS, 320, 0, stream>>>(gemb, W_g1, b_g1, gh);
    k_g2<<<N_MOLS, 64, 0, stream>>>(gh, W_g2, b_g2, out_graph);
}